// Round 3
// baseline (462.582 us; speedup 1.0000x reference)
//
#include <hip/hip_runtime.h>

typedef short bf16x8 __attribute__((ext_vector_type(8)));
typedef float f32x4 __attribute__((ext_vector_type(4)));
typedef unsigned int u32x4 __attribute__((ext_vector_type(4)));

#define MFMA16(a, b, c) __builtin_amdgcn_mfma_f32_16x16x32_bf16(a, b, c, 0, 0, 0)

__device__ __forceinline__ short f2bf(float f) {
  unsigned u = __builtin_bit_cast(unsigned, f);
  u += 0x7fffu + ((u >> 16) & 1u);   // round-to-nearest-even
  return (short)(u >> 16);
}

// async global->LDS, 16B per lane; LDS dest is wave-uniform base (+ lane*16 by HW)
__device__ __forceinline__ void gload16(const void* g, void* l) {
  __builtin_amdgcn_global_load_lds(
      (const __attribute__((address_space(1))) void*)g,
      (__attribute__((address_space(3))) void*)l, 16, 0, 0);
}

// Problem sizes (fixed)
// B=4, N=2048, D=512, H=8, DH=64, M = B*N = 8192, 3*H*DH = 1536
#define L2E 1.44269504088896f

// ---------------- prep kernels ----------------

__global__ __launch_bounds__(256) void cvt_bf16(const float* __restrict__ in,
                                                short* __restrict__ out) {
  size_t i = ((size_t)blockIdx.x * 256 + threadIdx.x) * 8;
  const float4* p = (const float4*)(in + i);
  float4 a = p[0], b = p[1];
  bf16x8 v;
  v[0] = f2bf(a.x); v[1] = f2bf(a.y); v[2] = f2bf(a.z); v[3] = f2bf(a.w);
  v[4] = f2bf(b.x); v[5] = f2bf(b.y); v[6] = f2bf(b.z); v[7] = f2bf(b.w);
  *(bf16x8*)(out + i) = v;
}

// in: fp32 [K][N] -> out: bf16 [N][K]
__global__ __launch_bounds__(256) void transpose_cvt(const float* __restrict__ in,
                                                     short* __restrict__ out,
                                                     int K, int N) {
  __shared__ short Ts[64][72];
  const int t = threadIdx.x;
  const int k0 = blockIdx.y * 64, n1 = blockIdx.x * 64;
  const int kk = t >> 2, nq = (t & 3) * 16;
  const float* src = in + (size_t)(k0 + kk) * N + n1 + nq;
#pragma unroll
  for (int i = 0; i < 16; ++i) Ts[nq + i][kk] = f2bf(src[i]);
  __syncthreads();
  const int n = t >> 2, kq = (t & 3) * 16;
  short* dst = out + (size_t)(n1 + n) * K + k0 + kq;
  *(bf16x8*)dst = *(const bf16x8*)&Ts[n][kq];
  *(bf16x8*)(dst + 8) = *(const bf16x8*)&Ts[n][kq + 8];
}

// ---------------- shared GEMM mainloop: C[128x128] tile, K=512 ----------------

__device__ __forceinline__ void gemm128_mainloop(const short* __restrict__ A,
                                                 const short* __restrict__ BT,
                                                 int m0, int n0,
                                                 short (*As)[40], short (*Bs)[40],
                                                 f32x4 acc[4][4]) {
  const int t = threadIdx.x;
  const int w = t >> 6, lane = t & 63, l15 = lane & 15, quad = lane >> 4;
  const int wm = (w & 1) * 64, wn = (w >> 1) * 64;
  const int srow = t >> 1, skg = (t & 1) * 16;
  const short* aptr = A + (size_t)(m0 + srow) * 512 + skg;
  const short* bptr = BT + (size_t)(n0 + srow) * 512 + skg;
  for (int k0 = 0; k0 < 512; k0 += 32) {
    __syncthreads();
    *(bf16x8*)&As[srow][skg]     = *(const bf16x8*)(aptr + k0);
    *(bf16x8*)&As[srow][skg + 8] = *(const bf16x8*)(aptr + k0 + 8);
    *(bf16x8*)&Bs[srow][skg]     = *(const bf16x8*)(bptr + k0);
    *(bf16x8*)&Bs[srow][skg + 8] = *(const bf16x8*)(bptr + k0 + 8);
    __syncthreads();
    bf16x8 af[4], bfr[4];
#pragma unroll
    for (int i = 0; i < 4; ++i) af[i] = *(const bf16x8*)&As[wm + i * 16 + l15][quad * 8];
#pragma unroll
    for (int j = 0; j < 4; ++j) bfr[j] = *(const bf16x8*)&Bs[wn + j * 16 + l15][quad * 8];
#pragma unroll
    for (int i = 0; i < 4; ++i)
#pragma unroll
      for (int j = 0; j < 4; ++j)
        acc[i][j] = MFMA16(af[i], bfr[j], acc[i][j]);
  }
}

// ---------------- K1: QKV projection ----------------

__global__ __launch_bounds__(256) void gemm_qkv(const short* __restrict__ A,
                                                const short* __restrict__ BT,
                                                short* __restrict__ q_ws,
                                                short* __restrict__ k_ws,
                                                short* __restrict__ v_t) {
  __shared__ short As[128][40];
  __shared__ short Bs[128][40];
  __shared__ short Ts[64][136];
  const int t = threadIdx.x;
  const int w = t >> 6, lane = t & 63, l15 = lane & 15, quad = lane >> 4;
  const int wm = (w & 1) * 64, wn = (w >> 1) * 64;
  const int m0 = blockIdx.y * 128, n0 = blockIdx.x * 128;
  f32x4 acc[4][4];
#pragma unroll
  for (int i = 0; i < 4; ++i)
#pragma unroll
    for (int j = 0; j < 4; ++j) acc[i][j] = (f32x4){0.f, 0.f, 0.f, 0.f};

  gemm128_mainloop(A, BT, m0, n0, As, Bs, acc);

  const int which = n0 >> 9;            // 0=q 1=k 2=v
  const int b = m0 >> 11, seq0 = m0 & 2047;
  if (which < 2) {
    short* dst = (which == 0) ? q_ws : k_ws;
    const float scale = (which == 0) ? (0.125f * L2E) : 1.0f;
#pragma unroll
    for (int i = 0; i < 4; ++i)
#pragma unroll
      for (int j = 0; j < 4; ++j)
#pragma unroll
        for (int r = 0; r < 4; ++r) {
          int m_loc = wm + i * 16 + quad * 4 + r;
          int col = n0 + wn + j * 16 + l15;
          int h = (col >> 6) & 7, d = col & 63;
          dst[((size_t)(b * 8 + h) * 2048 + seq0 + m_loc) * 64 + d] =
              f2bf(acc[i][j][r] * scale);
        }
  } else {
    for (int half = 0; half < 2; ++half) {
      __syncthreads();
      if ((w >> 1) == half) {
#pragma unroll
        for (int i = 0; i < 4; ++i)
#pragma unroll
          for (int j = 0; j < 4; ++j)
#pragma unroll
            for (int r = 0; r < 4; ++r)
              Ts[j * 16 + l15][wm + i * 16 + quad * 4 + r] = f2bf(acc[i][j][r]);
      }
      __syncthreads();
      const int hd = ((n0 + half * 64) >> 6) & 7;
      const int dp = t >> 2, sq = (t & 3) * 32;
      short* dstp = v_t + ((size_t)(b * 8 + hd) * 64 + dp) * 2048 + seq0 + sq;
#pragma unroll
      for (int u = 0; u < 4; ++u)
        *(bf16x8*)(dstp + u * 8) = *(const bf16x8*)&Ts[dp][sq + u * 8];
    }
  }
}

// ---------------- K2: fused flash attention (no-max softmax) ----------------
// v3.1 (v3 with buffer-stride fixes):
//  - Per-buffer stride for Ks/Bi is 8192 B (64*64*2), NOT 16384 (v3 bug:
//    odd-iteration K staging clobbered Pw; bias buf1 was past end of LDS).
//  - Bias read swizzle is XOR on the nt*32 term only (v3 bug: '+' carried
//    into the row index for nt>=2 on odd quads).
//  - Grid: bid = ((qt*4+b)<<3)|h -> round-robin puts all of head h on XCD h;
//    the 4 sibling blocks (b=0..3) sharing bias[h,qtile,:] co-reside -> bias
//    HBM-fetched ~once, served from that XCD's L2.  K/V per head (2 MB) also
//    L2-resident.
//  - Bias block-cooperatively staged (coalesced float4 -> *L2E ->
//    v_cvt_pk_bf16_f32 -> LDS bf16, double-buffered, row-bit2 XOR swizzle).
//  - V: per-wave register prefetch (8x b128 at body top, consumed at PV).
//  - LDS = 16K (Ks dbuf) + 8K (Pw) + 16K (Bi dbuf) = 40960 B -> 4 blocks/CU.

__global__ __launch_bounds__(256, 4) void attn_kernel(const short* __restrict__ q_ws,
                                                      const short* __restrict__ k_ws,
                                                      const short* __restrict__ v_t,
                                                      const float* __restrict__ bias,
                                                      short* __restrict__ attnO) {
  __shared__ short Ks[2][64][64];   // [buf][key][d]     16 KB (8192 B / buf)
  __shared__ short Pw[4][16][64];   // [wave][qrow][key]  8 KB
  __shared__ short Bi[2][64][64];   // [buf][qrow][key]  16 KB (bf16 bias*L2E)
  const int t = threadIdx.x;
  const int w = t >> 6, lane = t & 63, l15 = lane & 15, quad = lane >> 4;
  const int bid = blockIdx.x;
  const int h = bid & 7;                 // XCD = h under round-robin
  const int b = (bid >> 3) & 3;          // siblings 8 apart -> same XCD
  const int qt = bid >> 5;               // 0..31 (64-row q tiles)
  const int bh = b * 8 + h;
  const int q0 = qt * 64 + w * 16;       // wave's q rows
  const int cs = (quad * 16) ^ ((l15 & 7) << 4);   // K/P LDS read swizzle
  const int qswz = (quad & 1) << 6;                // bias LDS read swizzle

  // Q fragments
  const size_t qbase = ((size_t)bh * 2048 + q0 + l15) * 64 + quad * 8;
  bf16x8 aQ0 = *(const bf16x8*)(q_ws + qbase);
  bf16x8 aQ1 = *(const bf16x8*)(q_ws + qbase + 32);

  f32x4 O[4];
#pragma unroll
  for (int i = 0; i < 4; ++i) O[i] = (f32x4){0.f, 0.f, 0.f, 0.f};
  float lsum[4] = {0.f, 0.f, 0.f, 0.f};

  // --- K staging addressing (2 chunks/thread, swizzled global source) ---
  const int krow0 = w * 16 + (lane >> 3);          // ch = w*2
  const int kcol  = ((lane & 7) ^ (lane >> 3)) * 16;
  const char* kg0 = (const char*)k_ws + (size_t)(bh * 2048 + krow0) * 128 + kcol;
  const char* kg1 = kg0 + (size_t)8 * 128;         // ch = w*2+1
  char* kl0 = (char*)&Ks[0][0][0] + (w * 2) * 1024;
  char* kl1 = kl0 + 1024;

  // --- bias staging addressing ---
  const int brow = t >> 2;                          // 0..63 (block q row)
  const float* bsrc = bias + ((size_t)h * 2048 + qt * 64 + brow) * 2048 + (t & 3) * 16;
  // write base: row*128 + ((t&3)*32 ^ rowbit2<<6); two b128 at +0,+16
  char* bw0 = (char*)&Bi[0][0][0] + brow * 128 + (((t & 3) * 32) ^ (((t >> 4) & 1) << 6));
  // read base: (w*16+quad*4)*128 + 2*l15 ; + r*128 + (nt*32 ^ qswz)
  const char* br0 = (const char*)&Bi[0][0][0] + (w * 16 + quad * 4) * 128 + 2 * l15;

  // --- V register-prefetch addressing ---
  const char* vbase = (const char*)v_t + ((size_t)(bh * 64 + l15) * 2048 + quad * 8) * 2;

#define STAGE_K(BUF, J0)                                                       \
  do {                                                                         \
    gload16(kg0 + (size_t)(J0) * 128, kl0 + (BUF) * 8192);                     \
    gload16(kg1 + (size_t)(J0) * 128, kl1 + (BUF) * 8192);                     \
  } while (0)

#define BIAS_LOAD(BC, J0)                                                      \
  do {                                                                         \
    const float* s_ = bsrc + (J0);                                             \
    BC[0] = *(const float4*)(s_);                                              \
    BC[1] = *(const float4*)(s_ + 4);                                          \
    BC[2] = *(const float4*)(s_ + 8);                                          \
    BC[3] = *(const float4*)(s_ + 12);                                         \
  } while (0)

#define BIAS_WRITE(BUF, BC)                                                    \
  do {                                                                         \
    unsigned pk_[8];                                                           \
    _Pragma("unroll") for (int k_ = 0; k_ < 4; ++k_) {                         \
      float e0_ = BC[k_].x * L2E, e1_ = BC[k_].y * L2E;                        \
      float e2_ = BC[k_].z * L2E, e3_ = BC[k_].w * L2E;                        \
      asm("v_cvt_pk_bf16_f32 %0, %1, %2" : "=v"(pk_[k_ * 2]) : "v"(e0_), "v"(e1_)); \
      asm("v_cvt_pk_bf16_f32 %0, %1, %2" : "=v"(pk_[k_ * 2 + 1]) : "v"(e2_), "v"(e3_)); \
    }                                                                          \
    u32x4 w0_ = (u32x4){pk_[0], pk_[1], pk_[2], pk_[3]};                       \
    u32x4 w1_ = (u32x4){pk_[4], pk_[5], pk_[6], pk_[7]};                       \
    *(u32x4*)(bw0 + (BUF) * 8192) = w0_;                                       \
    *(u32x4*)(bw0 + (BUF) * 8192 + 16) = w1_;                                  \
  } while (0)

  // prologue: stage body 0
  {
    STAGE_K(0, 0);
    float4 bc[4];
    BIAS_LOAD(bc, 0);
    BIAS_WRITE(0, bc);
  }
  __syncthreads();

#pragma unroll 2
  for (int it = 0; it < 32; ++it) {
    const int cur = it & 1;
    const int j0 = it * 64;

    // V(it) register prefetch (used at PV, far away)
    bf16x8 vf[8];
#pragma unroll
    for (int dt = 0; dt < 4; ++dt) {
      const char* vp = vbase + (size_t)dt * 65536 + (size_t)j0 * 2;
      vf[dt * 2]     = *(const bf16x8*)(vp);
      vf[dt * 2 + 1] = *(const bf16x8*)(vp + 64);
    }

    // next-body staging: K via global_load_lds; bias via regs
    float4 bc[4];
    if (it < 31) {
      STAGE_K(cur ^ 1, j0 + 64);
      BIAS_LOAD(bc, j0 + 64);
    }

    // QK^T from Ks[cur]
    f32x4 S[4];
#pragma unroll
    for (int nt = 0; nt < 4; ++nt) {
      const char* kb = (const char*)&Ks[cur][0][0] + (nt * 16 + l15) * 128;
      bf16x8 k0 = *(const bf16x8*)(kb + cs);
      bf16x8 k1 = *(const bf16x8*)(kb + (cs ^ 64));
      f32x4 s = (f32x4){0.f, 0.f, 0.f, 0.f};
      s = MFMA16(aQ0, k0, s);
      s = MFMA16(aQ1, k1, s);
      S[nt] = s;
    }

    // write next bias tile (off critical path)
    if (it < 31) BIAS_WRITE(cur ^ 1, bc);

    // softmax: p = exp2(s + bias_l2e); lsum; P -> LDS (swizzled)
    const char* br = br0 + cur * 8192;
#pragma unroll
    for (int nt = 0; nt < 4; ++nt) {
      float p[4];
#pragma unroll
      for (int r = 0; r < 4; ++r) {
        unsigned u = *(const unsigned short*)(br + r * 128 + ((nt * 32) ^ qswz));
        float bv = __builtin_bit_cast(float, u << 16);
        p[r] = exp2f(S[nt][r] + bv);
        lsum[r] += p[r];
      }
      unsigned pk01, pk23;
      asm("v_cvt_pk_bf16_f32 %0, %1, %2" : "=v"(pk01) : "v"(p[0]), "v"(p[1]));
      asm("v_cvt_pk_bf16_f32 %0, %1, %2" : "=v"(pk23) : "v"(p[2]), "v"(p[3]));
      char* pb = (char*)&Pw[w][0][0];
      const int c0 = 2 * (nt * 16 + l15);
      const int q4 = quad * 4;
      *(short*)(pb + (q4 + 0) * 128 + (c0 ^ (((q4 + 0) & 7) << 4))) = (short)pk01;
      *(short*)(pb + (q4 + 1) * 128 + (c0 ^ (((q4 + 1) & 7) << 4))) = (short)(pk01 >> 16);
      *(short*)(pb + (q4 + 2) * 128 + (c0 ^ (((q4 + 2) & 7) << 4))) = (short)pk23;
      *(short*)(pb + (q4 + 3) * 128 + (c0 ^ (((q4 + 3) & 7) << 4))) = (short)(pk23 >> 16);
    }

    // P fragments + PV (V from registers)
    {
      const char* pr = (const char*)&Pw[w][0][0] + l15 * 128;
      bf16x8 aP0 = *(const bf16x8*)(pr + cs);
      bf16x8 aP1 = *(const bf16x8*)(pr + (cs ^ 64));
#pragma unroll
      for (int dt = 0; dt < 4; ++dt) {
        O[dt] = MFMA16(aP0, vf[dt * 2], O[dt]);
        O[dt] = MFMA16(aP1, vf[dt * 2 + 1], O[dt]);
      }
    }
    __syncthreads();
  }

  // one 16-lane reduction of l at the very end
#pragma unroll
  for (int off = 1; off <= 8; off <<= 1)
#pragma unroll
    for (int r = 0; r < 4; ++r) lsum[r] += __shfl_xor(lsum[r], off);
#pragma unroll
  for (int r = 0; r < 4; ++r) lsum[r] = 1.f / lsum[r];
#pragma unroll
  for (int dt = 0; dt < 4; ++dt)
#pragma unroll
    for (int r = 0; r < 4; ++r) {
      size_t row = (size_t)b * 2048 + q0 + quad * 4 + r;
      attnO[row * 512 + h * 64 + dt * 16 + l15] = f2bf(O[dt][r] * lsum[r]);
    }
#undef STAGE_K
#undef BIAS_LOAD
#undef BIAS_WRITE
}

// ---------------- K3: output projection (fp32 out) ----------------

__global__ __launch_bounds__(256) void gemm_out(const short* __restrict__ A,
                                                const short* __restrict__ BT,
                                                float* __restrict__ out) {
  __shared__ short As[128][40];
  __shared__ short Bs[128][40];
  const int t = threadIdx.x;
  const int w = t >> 6, lane = t & 63, l15 = lane & 15, quad = lane >> 4;
  const int wm = (w & 1) * 64, wn = (w >> 1) * 64;
  const int m0 = blockIdx.y * 128, n0 = blockIdx.x * 128;
  f32x4 acc[4][4];
#pragma unroll
  for (int i = 0; i < 4; ++i)
#pragma unroll
    for (int j = 0; j < 4; ++j) acc[i][j] = (f32x4){0.f, 0.f, 0.f, 0.f};

  gemm128_mainloop(A, BT, m0, n0, As, Bs, acc);

#pragma unroll
  for (int i = 0; i < 4; ++i)
#pragma unroll
    for (int j = 0; j < 4; ++j)
#pragma unroll
      for (int r = 0; r < 4; ++r)
        out[(size_t)(m0 + wm + i * 16 + quad * 4 + r) * 512 + n0 + wn + j * 16 + l15] =
            acc[i][j][r];
}

// ---------------- launch ----------------

extern "C" void kernel_launch(void* const* d_in, const int* in_sizes, int n_in,
                              void* d_out, int out_size, void* d_ws, size_t ws_size,
                              hipStream_t stream) {
  (void)in_sizes; (void)n_in; (void)out_size; (void)ws_size;
  const float* x        = (const float*)d_in[0];
  const float* pos_bias = (const float*)d_in[1];
  const float* w_qkv    = (const float*)d_in[2];
  const float* w_out    = (const float*)d_in[3];
  float* out = (float*)d_out;

  short* ws = (short*)d_ws;
  const size_t SEG = (size_t)32 * 2048 * 64;   // 4.19M elems
  short* q_ws  = ws;
  short* k_ws  = q_ws + SEG;
  short* v_t   = k_ws + SEG;
  short* attnO = v_t + SEG;
  short* xbf   = attnO + SEG;                  // [8192][512]
  short* wqkvT = xbf + SEG;                    // [1536][512]
  short* woutT = wqkvT + (size_t)1536 * 512;   // [512][512]

  cvt_bf16<<<2048, 256, 0, stream>>>(x, xbf);
  transpose_cvt<<<dim3(24, 8), 256, 0, stream>>>(w_qkv, wqkvT, 512, 1536);
  transpose_cvt<<<dim3(8, 8), 256, 0, stream>>>(w_out, woutT, 512, 512);
  gemm_qkv<<<dim3(12, 64), 256, 0, stream>>>(xbf, wqkvT, q_ws, k_ws, v_t);
  attn_kernel<<<1024, 256, 0, stream>>>(q_ws, k_ws, v_t, pos_bias, attnO);
  gemm_out<<<dim3(4, 64), 256, 0, stream>>>(attnO, woutT, out);
}

// Round 4
// 374.483 us; speedup vs baseline: 1.2353x; 1.2353x over previous
//
#include <hip/hip_runtime.h>

typedef short bf16x8 __attribute__((ext_vector_type(8)));
typedef float f32x4 __attribute__((ext_vector_type(4)));

#define MFMA16(a, b, c) __builtin_amdgcn_mfma_f32_16x16x32_bf16(a, b, c, 0, 0, 0)

__device__ __forceinline__ short f2bf(float f) {
  unsigned u = __builtin_bit_cast(unsigned, f);
  u += 0x7fffu + ((u >> 16) & 1u);   // round-to-nearest-even
  return (short)(u >> 16);
}

// async global->LDS, 16B per lane; LDS dest is wave-uniform base (+ lane*16 by HW)
__device__ __forceinline__ void gload16(const void* g, void* l) {
  __builtin_amdgcn_global_load_lds(
      (const __attribute__((address_space(1))) void*)g,
      (__attribute__((address_space(3))) void*)l, 16, 0, 0);
}

// Problem sizes (fixed)
// B=4, N=2048, D=512, H=8, DH=64, M = B*N = 8192, 3*H*DH = 1536
#define L2E 1.44269504088896f

// ---------------- prep kernels ----------------

__global__ __launch_bounds__(256) void cvt_bf16(const float* __restrict__ in,
                                                short* __restrict__ out) {
  size_t i = ((size_t)blockIdx.x * 256 + threadIdx.x) * 8;
  const float4* p = (const float4*)(in + i);
  float4 a = p[0], b = p[1];
  bf16x8 v;
  v[0] = f2bf(a.x); v[1] = f2bf(a.y); v[2] = f2bf(a.z); v[3] = f2bf(a.w);
  v[4] = f2bf(b.x); v[5] = f2bf(b.y); v[6] = f2bf(b.z); v[7] = f2bf(b.w);
  *(bf16x8*)(out + i) = v;
}

// in: fp32 [K][N] -> out: bf16 [N][K]
__global__ __launch_bounds__(256) void transpose_cvt(const float* __restrict__ in,
                                                     short* __restrict__ out,
                                                     int K, int N) {
  __shared__ short Ts[64][72];
  const int t = threadIdx.x;
  const int k0 = blockIdx.y * 64, n1 = blockIdx.x * 64;
  const int kk = t >> 2, nq = (t & 3) * 16;
  const float* src = in + (size_t)(k0 + kk) * N + n1 + nq;
#pragma unroll
  for (int i = 0; i < 16; ++i) Ts[nq + i][kk] = f2bf(src[i]);
  __syncthreads();
  const int n = t >> 2, kq = (t & 3) * 16;
  short* dst = out + (size_t)(n1 + n) * K + k0 + kq;
  *(bf16x8*)dst = *(const bf16x8*)&Ts[n][kq];
  *(bf16x8*)(dst + 8) = *(const bf16x8*)&Ts[n][kq + 8];
}

// ---------------- shared GEMM mainloop: C[128x128] tile, K=512 ----------------

__device__ __forceinline__ void gemm128_mainloop(const short* __restrict__ A,
                                                 const short* __restrict__ BT,
                                                 int m0, int n0,
                                                 short (*As)[40], short (*Bs)[40],
                                                 f32x4 acc[4][4]) {
  const int t = threadIdx.x;
  const int w = t >> 6, lane = t & 63, l15 = lane & 15, quad = lane >> 4;
  const int wm = (w & 1) * 64, wn = (w >> 1) * 64;
  const int srow = t >> 1, skg = (t & 1) * 16;
  const short* aptr = A + (size_t)(m0 + srow) * 512 + skg;
  const short* bptr = BT + (size_t)(n0 + srow) * 512 + skg;
  for (int k0 = 0; k0 < 512; k0 += 32) {
    __syncthreads();
    *(bf16x8*)&As[srow][skg]     = *(const bf16x8*)(aptr + k0);
    *(bf16x8*)&As[srow][skg + 8] = *(const bf16x8*)(aptr + k0 + 8);
    *(bf16x8*)&Bs[srow][skg]     = *(const bf16x8*)(bptr + k0);
    *(bf16x8*)&Bs[srow][skg + 8] = *(const bf16x8*)(bptr + k0 + 8);
    __syncthreads();
    bf16x8 af[4], bfr[4];
#pragma unroll
    for (int i = 0; i < 4; ++i) af[i] = *(const bf16x8*)&As[wm + i * 16 + l15][quad * 8];
#pragma unroll
    for (int j = 0; j < 4; ++j) bfr[j] = *(const bf16x8*)&Bs[wn + j * 16 + l15][quad * 8];
#pragma unroll
    for (int i = 0; i < 4; ++i)
#pragma unroll
      for (int j = 0; j < 4; ++j)
        acc[i][j] = MFMA16(af[i], bfr[j], acc[i][j]);
  }
}

// ---------------- K1: QKV projection ----------------

__global__ __launch_bounds__(256) void gemm_qkv(const short* __restrict__ A,
                                                const short* __restrict__ BT,
                                                short* __restrict__ q_ws,
                                                short* __restrict__ k_ws,
                                                short* __restrict__ v_t) {
  __shared__ short As[128][40];
  __shared__ short Bs[128][40];
  __shared__ short Ts[64][136];
  const int t = threadIdx.x;
  const int w = t >> 6, lane = t & 63, l15 = lane & 15, quad = lane >> 4;
  const int wm = (w & 1) * 64, wn = (w >> 1) * 64;
  const int m0 = blockIdx.y * 128, n0 = blockIdx.x * 128;
  f32x4 acc[4][4];
#pragma unroll
  for (int i = 0; i < 4; ++i)
#pragma unroll
    for (int j = 0; j < 4; ++j) acc[i][j] = (f32x4){0.f, 0.f, 0.f, 0.f};

  gemm128_mainloop(A, BT, m0, n0, As, Bs, acc);

  const int which = n0 >> 9;            // 0=q 1=k 2=v
  const int b = m0 >> 11, seq0 = m0 & 2047;
  if (which < 2) {
    short* dst = (which == 0) ? q_ws : k_ws;
    const float scale = (which == 0) ? (0.125f * L2E) : 1.0f;
#pragma unroll
    for (int i = 0; i < 4; ++i)
#pragma unroll
      for (int j = 0; j < 4; ++j)
#pragma unroll
        for (int r = 0; r < 4; ++r) {
          int m_loc = wm + i * 16 + quad * 4 + r;
          int col = n0 + wn + j * 16 + l15;
          int h = (col >> 6) & 7, d = col & 63;
          dst[((size_t)(b * 8 + h) * 2048 + seq0 + m_loc) * 64 + d] =
              f2bf(acc[i][j][r] * scale);
        }
  } else {
    for (int half = 0; half < 2; ++half) {
      __syncthreads();
      if ((w >> 1) == half) {
#pragma unroll
        for (int i = 0; i < 4; ++i)
#pragma unroll
          for (int j = 0; j < 4; ++j)
#pragma unroll
            for (int r = 0; r < 4; ++r)
              Ts[j * 16 + l15][wm + i * 16 + quad * 4 + r] = f2bf(acc[i][j][r]);
      }
      __syncthreads();
      const int hd = ((n0 + half * 64) >> 6) & 7;
      const int dp = t >> 2, sq = (t & 3) * 32;
      short* dstp = v_t + ((size_t)(b * 8 + hd) * 64 + dp) * 2048 + seq0 + sq;
#pragma unroll
      for (int u = 0; u < 4; ++u)
        *(bf16x8*)(dstp + u * 8) = *(const bf16x8*)&Ts[dp][sq + u * 8];
    }
  }
}

// ---------------- K2: fused flash attention (no-max softmax) ----------------
// v4 = R1's verified 166us structure (K,V double-buffered LDS via
// global_load_lds, XOR-swizzled; P via Pw LDS; bias as scattered ping-pong
// register prefetch) with ONE change: the XCD-pinned grid decode verified in
// v3.1 (FETCH 381->194 MB).  bid = ((qt*4+b)<<3)|h -> round-robin puts all
// blocks of head h on XCD h; the 4 sibling blocks (b=0..3) sharing
// bias[h, qtile, :] co-reside, so bias is HBM-fetched ~once and L2-served.
// v3.1's V-in-registers + cooperative bias LDS are REVERTED: they spilled
// (WRITE_SIZE 51->160 MB of scratch traffic) and cost +80us.

#define ATTN_STAGE(BUFD, J0N)                                                  \
  do {                                                                         \
    _Pragma("unroll") for (int i_ = 0; i_ < 2; ++i_) {                         \
      const int ch_ = w * 2 + i_;                                              \
      const int off_ = ch_ * 1024 + lane * 16;                                 \
      const int row_ = off_ >> 7;                                              \
      const int col_ = (off_ & 127) ^ ((row_ & 7) << 4);                       \
      const char* gk_ = (const char*)k_ws +                                    \
          ((size_t)bh * 2048 + (size_t)(J0N) + row_) * 128 + col_;             \
      const char* gv_ = (const char*)v_t +                                     \
          ((size_t)bh * 64 + row_) * 4096 + (size_t)(J0N) * 2 + col_;          \
      gload16(gk_, (char*)&Ks[BUFD][0][0] + ch_ * 1024);                       \
      gload16(gv_, (char*)&Vs[BUFD][0][0] + ch_ * 1024);                       \
    }                                                                          \
  } while (0)

#define ATTN_LOADB(BV, J0N)                                                    \
  do {                                                                         \
    _Pragma("unroll") for (int nt_ = 0; nt_ < 4; ++nt_)                        \
        _Pragma("unroll") for (int r_ = 0; r_ < 4; ++r_)                       \
            BV[nt_][r_] = brow[r_][(J0N) + nt_ * 16];                          \
  } while (0)

#define ATTN_BODY(BUFC, BVC, BVN, J0N, DONEXT)                                 \
  do {                                                                         \
    if (DONEXT) {                                                              \
      ATTN_STAGE((BUFC) ^ 1, (J0N));                                           \
      ATTN_LOADB(BVN, (J0N));                                                  \
    }                                                                          \
    f32x4 S_[4];                                                               \
    _Pragma("unroll") for (int nt_ = 0; nt_ < 4; ++nt_) {                      \
      const char* kb_ = (const char*)&Ks[BUFC][0][0] + (nt_ * 16 + l15) * 128; \
      bf16x8 k0_ = *(const bf16x8*)(kb_ + cs);                                 \
      bf16x8 k1_ = *(const bf16x8*)(kb_ + (cs ^ 64));                          \
      f32x4 s_ = (f32x4){0.f, 0.f, 0.f, 0.f};                                  \
      s_ = MFMA16(aQ0, k0_, s_);                                               \
      s_ = MFMA16(aQ1, k1_, s_);                                               \
      S_[nt_] = s_;                                                            \
    }                                                                          \
    _Pragma("unroll") for (int nt_ = 0; nt_ < 4; ++nt_) {                      \
      float p0_ = exp2f(fmaf(BVC[nt_][0], L2E, S_[nt_][0]));                   \
      float p1_ = exp2f(fmaf(BVC[nt_][1], L2E, S_[nt_][1]));                   \
      float p2_ = exp2f(fmaf(BVC[nt_][2], L2E, S_[nt_][2]));                   \
      float p3_ = exp2f(fmaf(BVC[nt_][3], L2E, S_[nt_][3]));                   \
      lsum[0] += p0_; lsum[1] += p1_; lsum[2] += p2_; lsum[3] += p3_;          \
      unsigned pk01_, pk23_;                                                   \
      asm("v_cvt_pk_bf16_f32 %0, %1, %2" : "=v"(pk01_) : "v"(p0_), "v"(p1_)); \
      asm("v_cvt_pk_bf16_f32 %0, %1, %2" : "=v"(pk23_) : "v"(p2_), "v"(p3_)); \
      char* pb_ = (char*)&Pw[w][0][0];                                         \
      const int c0_ = 2 * (nt_ * 16 + l15);                                    \
      const int q4_ = quad * 4;                                                \
      *(short*)(pb_ + (q4_ + 0) * 128 + (c0_ ^ (((q4_ + 0) & 7) << 4))) =      \
          (short)pk01_;                                                        \
      *(short*)(pb_ + (q4_ + 1) * 128 + (c0_ ^ (((q4_ + 1) & 7) << 4))) =      \
          (short)(pk01_ >> 16);                                                \
      *(short*)(pb_ + (q4_ + 2) * 128 + (c0_ ^ (((q4_ + 2) & 7) << 4))) =      \
          (short)pk23_;                                                        \
      *(short*)(pb_ + (q4_ + 3) * 128 + (c0_ ^ (((q4_ + 3) & 7) << 4))) =      \
          (short)(pk23_ >> 16);                                                \
    }                                                                          \
    {                                                                          \
      const char* pr_ = (const char*)&Pw[w][0][0] + l15 * 128;                 \
      bf16x8 aP0 = *(const bf16x8*)(pr_ + cs);                                 \
      bf16x8 aP1 = *(const bf16x8*)(pr_ + (cs ^ 64));                          \
      _Pragma("unroll") for (int dt_ = 0; dt_ < 4; ++dt_) {                    \
        const char* vb_ =                                                      \
            (const char*)&Vs[BUFC][0][0] + (dt_ * 16 + l15) * 128;             \
        bf16x8 v0_ = *(const bf16x8*)(vb_ + cs);                               \
        bf16x8 v1_ = *(const bf16x8*)(vb_ + (cs ^ 64));                        \
        O[dt_] = MFMA16(aP0, v0_, O[dt_]);                                     \
        O[dt_] = MFMA16(aP1, v1_, O[dt_]);                                     \
      }                                                                        \
    }                                                                          \
    __syncthreads();                                                           \
  } while (0)

__global__ __launch_bounds__(256, 4) void attn_kernel(const short* __restrict__ q_ws,
                                                      const short* __restrict__ k_ws,
                                                      const short* __restrict__ v_t,
                                                      const float* __restrict__ bias,
                                                      short* __restrict__ attnO) {
  __shared__ short Ks[2][64][64];   // [buf][key][d]   8KB x2
  __shared__ short Vs[2][64][64];   // [buf][d][seq]   8KB x2
  __shared__ short Pw[4][16][64];   // [wave][qrow][key] 8KB
  const int t = threadIdx.x;
  const int w = t >> 6, lane = t & 63, l15 = lane & 15, quad = lane >> 4;
  const int bid = blockIdx.x;
  const int h = bid & 7;                 // XCD = h under round-robin dispatch
  const int b = (bid >> 3) & 3;          // siblings 8 apart -> same XCD
  const int qb = bid >> 5;               // 0..31 (64-row q tiles)
  const int bh = b * 8 + h;
  const int q0 = qb * 64 + w * 16;
  const int cs = (quad * 16) ^ ((l15 & 7) << 4);   // shared LDS read swizzle

  const size_t qbase = ((size_t)bh * 2048 + q0 + l15) * 64 + quad * 8;
  bf16x8 aQ0 = *(const bf16x8*)(q_ws + qbase);
  bf16x8 aQ1 = *(const bf16x8*)(q_ws + qbase + 32);

  f32x4 O[4];
#pragma unroll
  for (int i = 0; i < 4; ++i) O[i] = (f32x4){0.f, 0.f, 0.f, 0.f};
  float lsum[4] = {0.f, 0.f, 0.f, 0.f};

  const float* brow[4];
#pragma unroll
  for (int r = 0; r < 4; ++r)
    brow[r] = bias + ((size_t)h * 2048 + q0 + quad * 4 + r) * 2048 + l15;

  float bvA[4][4], bvB[4][4];
  ATTN_STAGE(0, 0);
  ATTN_LOADB(bvA, 0);
  __syncthreads();

  for (int it = 0; it < 16; ++it) {
    const int j0 = it * 128;
    ATTN_BODY(0, bvA, bvB, j0 + 64, 1);
    ATTN_BODY(1, bvB, bvA, j0 + 128, (it < 15));
  }

  // one 16-lane reduction of l at the very end
#pragma unroll
  for (int off = 1; off <= 8; off <<= 1)
#pragma unroll
    for (int r = 0; r < 4; ++r) lsum[r] += __shfl_xor(lsum[r], off);
#pragma unroll
  for (int r = 0; r < 4; ++r) lsum[r] = 1.f / lsum[r];
#pragma unroll
  for (int dt = 0; dt < 4; ++dt)
#pragma unroll
    for (int r = 0; r < 4; ++r) {
      size_t row = (size_t)b * 2048 + q0 + quad * 4 + r;
      attnO[row * 512 + h * 64 + dt * 16 + l15] = f2bf(O[dt][r] * lsum[r]);
    }
#undef ATTN_STAGE
#undef ATTN_LOADB
#undef ATTN_BODY
}

// ---------------- K3: output projection (fp32 out) ----------------

__global__ __launch_bounds__(256) void gemm_out(const short* __restrict__ A,
                                                const short* __restrict__ BT,
                                                float* __restrict__ out) {
  __shared__ short As[128][40];
  __shared__ short Bs[128][40];
  const int t = threadIdx.x;
  const int w = t >> 6, lane = t & 63, l15 = lane & 15, quad = lane >> 4;
  const int wm = (w & 1) * 64, wn = (w >> 1) * 64;
  const int m0 = blockIdx.y * 128, n0 = blockIdx.x * 128;
  f32x4 acc[4][4];
#pragma unroll
  for (int i = 0; i < 4; ++i)
#pragma unroll
    for (int j = 0; j < 4; ++j) acc[i][j] = (f32x4){0.f, 0.f, 0.f, 0.f};

  gemm128_mainloop(A, BT, m0, n0, As, Bs, acc);

#pragma unroll
  for (int i = 0; i < 4; ++i)
#pragma unroll
    for (int j = 0; j < 4; ++j)
#pragma unroll
      for (int r = 0; r < 4; ++r)
        out[(size_t)(m0 + wm + i * 16 + quad * 4 + r) * 512 + n0 + wn + j * 16 + l15] =
            acc[i][j][r];
}

// ---------------- launch ----------------

extern "C" void kernel_launch(void* const* d_in, const int* in_sizes, int n_in,
                              void* d_out, int out_size, void* d_ws, size_t ws_size,
                              hipStream_t stream) {
  (void)in_sizes; (void)n_in; (void)out_size; (void)ws_size;
  const float* x        = (const float*)d_in[0];
  const float* pos_bias = (const float*)d_in[1];
  const float* w_qkv    = (const float*)d_in[2];
  const float* w_out    = (const float*)d_in[3];
  float* out = (float*)d_out;

  short* ws = (short*)d_ws;
  const size_t SEG = (size_t)32 * 2048 * 64;   // 4.19M elems
  short* q_ws  = ws;
  short* k_ws  = q_ws + SEG;
  short* v_t   = k_ws + SEG;
  short* attnO = v_t + SEG;
  short* xbf   = attnO + SEG;                  // [8192][512]
  short* wqkvT = xbf + SEG;                    // [1536][512]
  short* woutT = wqkvT + (size_t)1536 * 512;   // [512][512]

  cvt_bf16<<<2048, 256, 0, stream>>>(x, xbf);
  transpose_cvt<<<dim3(24, 8), 256, 0, stream>>>(w_qkv, wqkvT, 512, 1536);
  transpose_cvt<<<dim3(8, 8), 256, 0, stream>>>(w_out, woutT, 512, 512);
  gemm_qkv<<<dim3(12, 64), 256, 0, stream>>>(xbf, wqkvT, q_ws, k_ws, v_t);
  attn_kernel<<<1024, 256, 0, stream>>>(q_ws, k_ws, v_t, pos_bias, attnO);
  gemm_out<<<dim3(4, 64), 256, 0, stream>>>(attnO, woutT, out);
}

// Round 7
// 368.904 us; speedup vs baseline: 1.2539x; 1.0151x over previous
//
#include <hip/hip_runtime.h>

typedef short bf16x8 __attribute__((ext_vector_type(8)));
typedef float f32x4 __attribute__((ext_vector_type(4)));

#define MFMA16(a, b, c) __builtin_amdgcn_mfma_f32_16x16x32_bf16(a, b, c, 0, 0, 0)

__device__ __forceinline__ short f2bf(float f) {
  unsigned u = __builtin_bit_cast(unsigned, f);
  u += 0x7fffu + ((u >> 16) & 1u);   // round-to-nearest-even
  return (short)(u >> 16);
}

// async global->LDS, 16B per lane; LDS dest is wave-uniform base (+ lane*16 by HW)
__device__ __forceinline__ void gload16(const void* g, void* l) {
  __builtin_amdgcn_global_load_lds(
      (const __attribute__((address_space(1))) void*)g,
      (__attribute__((address_space(3))) void*)l, 16, 0, 0);
}

// Problem sizes (fixed)
// B=4, N=2048, D=512, H=8, DH=64, M = B*N = 8192, 3*H*DH = 1536
#define L2E 1.44269504088896f

// ---------------- prep kernels (verified R4 versions) ----------------

__global__ __launch_bounds__(256) void cvt_bf16(const float* __restrict__ in,
                                                short* __restrict__ out) {
  size_t i = ((size_t)blockIdx.x * 256 + threadIdx.x) * 8;
  const float4* p = (const float4*)(in + i);
  float4 a = p[0], b = p[1];
  bf16x8 v;
  v[0] = f2bf(a.x); v[1] = f2bf(a.y); v[2] = f2bf(a.z); v[3] = f2bf(a.w);
  v[4] = f2bf(b.x); v[5] = f2bf(b.y); v[6] = f2bf(b.z); v[7] = f2bf(b.w);
  *(bf16x8*)(out + i) = v;
}

// in: fp32 [K][N] -> out: bf16 [N][K]
__global__ __launch_bounds__(256) void transpose_cvt(const float* __restrict__ in,
                                                     short* __restrict__ out,
                                                     int K, int N) {
  __shared__ short Ts[64][72];
  const int t = threadIdx.x;
  const int k0 = blockIdx.y * 64, n1 = blockIdx.x * 64;
  const int kk = t >> 2, nq = (t & 3) * 16;
  const float* src = in + (size_t)(k0 + kk) * N + n1 + nq;
#pragma unroll
  for (int i = 0; i < 16; ++i) Ts[nq + i][kk] = f2bf(src[i]);
  __syncthreads();
  const int n = t >> 2, kq = (t & 3) * 16;
  short* dst = out + (size_t)(n1 + n) * K + k0 + kq;
  *(bf16x8*)dst = *(const bf16x8*)&Ts[n][kq];
  *(bf16x8*)(dst + 8) = *(const bf16x8*)&Ts[n][kq + 8];
}

// ---------------- shared async GEMM mainloop: C[128x128] tile, K=512 ----------------
// A: bf16 [M][512] row-major; BT: bf16 [Ncols][512].
// 2-phase pipeline: double-buffered global_load_lds staging (4x16B per thread
// per K-step), ONE barrier per K-step.  LDS tile [128][32] shorts (64B rows),
// XOR-swizzle col ^= ((row>>1)&3)<<4 applied on the pre-swizzled global source
// (m173: global_load_lds writes linearly) and on the ds_read_b128 address.
// Every 8-consecutive-lane group hits 8 distinct 16B slots mod 128B (same
// structure as the attn cs pattern that measured 0 conflicts).

__device__ __forceinline__ void gemm128_async(const short* __restrict__ A,
                                              const short* __restrict__ BT,
                                              int m0, int n0,
                                              char* As, char* Bs,
                                              f32x4 acc[4][4]) {
  const int t = threadIdx.x;
  const int w = t >> 6, lane = t & 63, l15 = lane & 15, quad = lane >> 4;
  const int wm = (w & 1) * 64, wn = (w >> 1) * 64;
  // staging: wave w stages rows [w*32, w*32+32) of both tiles as 2 chunks of
  // 16 rows; lane l covers row chunk0+(l>>2), colbyte ((l&3)^((l>>3)&3))<<4
  const int scol = ((lane & 3) ^ ((lane >> 3) & 3)) << 4;
  const char* ag = (const char*)A + (size_t)(m0 + w * 32 + (lane >> 2)) * 1024 + scol;
  const char* bg = (const char*)BT + (size_t)(n0 + w * 32 + (lane >> 2)) * 1024 + scol;
  char* al = As + w * 2048;
  char* bl = Bs + w * 2048;
  // fragment reads: row wm+i*16+l15, logical col quad*16 -> swizzled slot
  const int rsw = (quad ^ ((l15 >> 1) & 3)) << 4;
  const int ra = (wm + l15) * 64 + rsw;
  const int rb = (wn + l15) * 64 + rsw;

#define GQ_STAGE(BUF, KB)                                                      \
  do {                                                                         \
    gload16(ag + (KB), al + (BUF) * 8192);                                     \
    gload16(ag + 16384 + (KB), al + (BUF) * 8192 + 1024);                      \
    gload16(bg + (KB), bl + (BUF) * 8192);                                     \
    gload16(bg + 16384 + (KB), bl + (BUF) * 8192 + 1024);                      \
  } while (0)

  GQ_STAGE(0, 0);
  __syncthreads();
#pragma unroll 2
  for (int s = 0; s < 16; ++s) {
    const int buf = s & 1;
    if (s < 15) GQ_STAGE(buf ^ 1, (s + 1) * 64);
    bf16x8 af[4], bfr[4];
#pragma unroll
    for (int i = 0; i < 4; ++i)
      af[i] = *(const bf16x8*)(As + buf * 8192 + ra + i * 1024);
#pragma unroll
    for (int j = 0; j < 4; ++j)
      bfr[j] = *(const bf16x8*)(Bs + buf * 8192 + rb + j * 1024);
#pragma unroll
    for (int i = 0; i < 4; ++i)
#pragma unroll
      for (int j = 0; j < 4; ++j)
        acc[i][j] = MFMA16(af[i], bfr[j], acc[i][j]);
    __syncthreads();
  }
#undef GQ_STAGE
}

// ---------------- K1: QKV projection ----------------

__global__ __launch_bounds__(256) void gemm_qkv(const short* __restrict__ A,
                                                const short* __restrict__ BT,
                                                short* __restrict__ q_ws,
                                                short* __restrict__ k_ws,
                                                short* __restrict__ v_t) {
  __shared__ short As[2][128][32];
  __shared__ short Bs[2][128][32];
  __shared__ short Ts[64][136];
  const int t = threadIdx.x;
  const int w = t >> 6, lane = t & 63, l15 = lane & 15, quad = lane >> 4;
  const int wm = (w & 1) * 64, wn = (w >> 1) * 64;
  const int m0 = blockIdx.y * 128, n0 = blockIdx.x * 128;
  f32x4 acc[4][4];
#pragma unroll
  for (int i = 0; i < 4; ++i)
#pragma unroll
    for (int j = 0; j < 4; ++j) acc[i][j] = (f32x4){0.f, 0.f, 0.f, 0.f};

  gemm128_async(A, BT, m0, n0, (char*)&As[0][0][0], (char*)&Bs[0][0][0], acc);

  const int which = n0 >> 9;            // 0=q 1=k 2=v
  const int b = m0 >> 11, seq0 = m0 & 2047;
  if (which < 2) {
    short* dst = (which == 0) ? q_ws : k_ws;
    const float scale = (which == 0) ? (0.125f * L2E) : 1.0f;
#pragma unroll
    for (int i = 0; i < 4; ++i)
#pragma unroll
      for (int j = 0; j < 4; ++j)
#pragma unroll
        for (int r = 0; r < 4; ++r) {
          int m_loc = wm + i * 16 + quad * 4 + r;
          int col = n0 + wn + j * 16 + l15;
          int h = (col >> 6) & 7, d = col & 63;
          dst[((size_t)(b * 8 + h) * 2048 + seq0 + m_loc) * 64 + d] =
              f2bf(acc[i][j][r] * scale);
        }
  } else {
    for (int half = 0; half < 2; ++half) {
      __syncthreads();
      if ((w >> 1) == half) {
#pragma unroll
        for (int i = 0; i < 4; ++i)
#pragma unroll
          for (int j = 0; j < 4; ++j)
#pragma unroll
            for (int r = 0; r < 4; ++r)
              Ts[j * 16 + l15][wm + i * 16 + quad * 4 + r] = f2bf(acc[i][j][r]);
      }
      __syncthreads();
      const int hd = ((n0 + half * 64) >> 6) & 7;
      const int dp = t >> 2, sq = (t & 3) * 32;
      short* dstp = v_t + ((size_t)(b * 8 + hd) * 64 + dp) * 2048 + seq0 + sq;
#pragma unroll
      for (int u = 0; u < 4; ++u)
        *(bf16x8*)(dstp + u * 8) = *(const bf16x8*)&Ts[dp][sq + u * 8];
    }
  }
}

// ---------------- K2: fused flash attention (no-max softmax) ----------------
// Verified R4 structure, UNCHANGED (control):
// K,V double-buffered LDS via global_load_lds, XOR-swizzled reads; P via Pw
// LDS roundtrip; bias scattered ping-pong register prefetch; XCD-pinned grid
// (bid = ((qt*4+b)<<3)|h -> head h lands on XCD h; 4 sibling batches share
// bias tile via that XCD's L2).

#define ATTN_STAGE(BUFD, J0N)                                                  \
  do {                                                                         \
    _Pragma("unroll") for (int i_ = 0; i_ < 2; ++i_) {                         \
      const int ch_ = w * 2 + i_;                                              \
      const int off_ = ch_ * 1024 + lane * 16;                                 \
      const int row_ = off_ >> 7;                                              \
      const int col_ = (off_ & 127) ^ ((row_ & 7) << 4);                       \
      const char* gk_ = (const char*)k_ws +                                    \
          ((size_t)bh * 2048 + (size_t)(J0N) + row_) * 128 + col_;             \
      const char* gv_ = (const char*)v_t +                                     \
          ((size_t)bh * 64 + row_) * 4096 + (size_t)(J0N) * 2 + col_;          \
      gload16(gk_, (char*)&Ks[BUFD][0][0] + ch_ * 1024);                       \
      gload16(gv_, (char*)&Vs[BUFD][0][0] + ch_ * 1024);                       \
    }                                                                          \
  } while (0)

#define ATTN_LOADB(BV, J0N)                                                    \
  do {                                                                         \
    _Pragma("unroll") for (int nt_ = 0; nt_ < 4; ++nt_)                        \
        _Pragma("unroll") for (int r_ = 0; r_ < 4; ++r_)                       \
            BV[nt_][r_] = brow[r_][(J0N) + nt_ * 16];                          \
  } while (0)

#define ATTN_BODY(BUFC, BVC, BVN, J0N, DONEXT)                                 \
  do {                                                                         \
    if (DONEXT) {                                                              \
      ATTN_STAGE((BUFC) ^ 1, (J0N));                                           \
      ATTN_LOADB(BVN, (J0N));                                                  \
    }                                                                          \
    f32x4 S_[4];                                                               \
    _Pragma("unroll") for (int nt_ = 0; nt_ < 4; ++nt_) {                      \
      const char* kb_ = (const char*)&Ks[BUFC][0][0] + (nt_ * 16 + l15) * 128; \
      bf16x8 k0_ = *(const bf16x8*)(kb_ + cs);                                 \
      bf16x8 k1_ = *(const bf16x8*)(kb_ + (cs ^ 64));                          \
      f32x4 s_ = (f32x4){0.f, 0.f, 0.f, 0.f};                                  \
      s_ = MFMA16(aQ0, k0_, s_);                                               \
      s_ = MFMA16(aQ1, k1_, s_);                                               \
      S_[nt_] = s_;                                                            \
    }                                                                          \
    _Pragma("unroll") for (int nt_ = 0; nt_ < 4; ++nt_) {                      \
      float p0_ = exp2f(fmaf(BVC[nt_][0], L2E, S_[nt_][0]));                   \
      float p1_ = exp2f(fmaf(BVC[nt_][1], L2E, S_[nt_][1]));                   \
      float p2_ = exp2f(fmaf(BVC[nt_][2], L2E, S_[nt_][2]));                   \
      float p3_ = exp2f(fmaf(BVC[nt_][3], L2E, S_[nt_][3]));                   \
      lsum[0] += p0_; lsum[1] += p1_; lsum[2] += p2_; lsum[3] += p3_;          \
      unsigned pk01_, pk23_;                                                   \
      asm("v_cvt_pk_bf16_f32 %0, %1, %2" : "=v"(pk01_) : "v"(p0_), "v"(p1_)); \
      asm("v_cvt_pk_bf16_f32 %0, %1, %2" : "=v"(pk23_) : "v"(p2_), "v"(p3_)); \
      char* pb_ = (char*)&Pw[w][0][0];                                         \
      const int c0_ = 2 * (nt_ * 16 + l15);                                    \
      const int q4_ = quad * 4;                                                \
      *(short*)(pb_ + (q4_ + 0) * 128 + (c0_ ^ (((q4_ + 0) & 7) << 4))) =      \
          (short)pk01_;                                                        \
      *(short*)(pb_ + (q4_ + 1) * 128 + (c0_ ^ (((q4_ + 1) & 7) << 4))) =      \
          (short)(pk01_ >> 16);                                                \
      *(short*)(pb_ + (q4_ + 2) * 128 + (c0_ ^ (((q4_ + 2) & 7) << 4))) =      \
          (short)pk23_;                                                        \
      *(short*)(pb_ + (q4_ + 3) * 128 + (c0_ ^ (((q4_ + 3) & 7) << 4))) =      \
          (short)(pk23_ >> 16);                                                \
    }                                                                          \
    {                                                                          \
      const char* pr_ = (const char*)&Pw[w][0][0] + l15 * 128;                 \
      bf16x8 aP0 = *(const bf16x8*)(pr_ + cs);                                 \
      bf16x8 aP1 = *(const bf16x8*)(pr_ + (cs ^ 64));                          \
      _Pragma("unroll") for (int dt_ = 0; dt_ < 4; ++dt_) {                    \
        const char* vb_ =                                                      \
            (const char*)&Vs[BUFC][0][0] + (dt_ * 16 + l15) * 128;             \
        bf16x8 v0_ = *(const bf16x8*)(vb_ + cs);                               \
        bf16x8 v1_ = *(const bf16x8*)(vb_ + (cs ^ 64));                        \
        O[dt_] = MFMA16(aP0, v0_, O[dt_]);                                     \
        O[dt_] = MFMA16(aP1, v1_, O[dt_]);                                     \
      }                                                                        \
    }                                                                          \
    __syncthreads();                                                           \
  } while (0)

__global__ __launch_bounds__(256, 4) void attn_kernel(const short* __restrict__ q_ws,
                                                      const short* __restrict__ k_ws,
                                                      const short* __restrict__ v_t,
                                                      const float* __restrict__ bias,
                                                      short* __restrict__ attnO) {
  __shared__ short Ks[2][64][64];   // [buf][key][d]   8KB x2
  __shared__ short Vs[2][64][64];   // [buf][d][seq]   8KB x2
  __shared__ short Pw[4][16][64];   // [wave][qrow][key] 8KB
  const int t = threadIdx.x;
  const int w = t >> 6, lane = t & 63, l15 = lane & 15, quad = lane >> 4;
  const int bid = blockIdx.x;
  const int h = bid & 7;                 // XCD = h under round-robin dispatch
  const int b = (bid >> 3) & 3;          // siblings 8 apart -> same XCD
  const int qb = bid >> 5;               // 0..31 (64-row q tiles)
  const int bh = b * 8 + h;
  const int q0 = qb * 64 + w * 16;
  const int cs = (quad * 16) ^ ((l15 & 7) << 4);   // shared LDS read swizzle

  const size_t qbase = ((size_t)bh * 2048 + q0 + l15) * 64 + quad * 8;
  bf16x8 aQ0 = *(const bf16x8*)(q_ws + qbase);
  bf16x8 aQ1 = *(const bf16x8*)(q_ws + qbase + 32);

  f32x4 O[4];
#pragma unroll
  for (int i = 0; i < 4; ++i) O[i] = (f32x4){0.f, 0.f, 0.f, 0.f};
  float lsum[4] = {0.f, 0.f, 0.f, 0.f};

  const float* brow[4];
#pragma unroll
  for (int r = 0; r < 4; ++r)
    brow[r] = bias + ((size_t)h * 2048 + q0 + quad * 4 + r) * 2048 + l15;

  float bvA[4][4], bvB[4][4];
  ATTN_STAGE(0, 0);
  ATTN_LOADB(bvA, 0);
  __syncthreads();

  for (int it = 0; it < 16; ++it) {
    const int j0 = it * 128;
    ATTN_BODY(0, bvA, bvB, j0 + 64, 1);
    ATTN_BODY(1, bvB, bvA, j0 + 128, (it < 15));
  }

  // one 16-lane reduction of l at the very end
#pragma unroll
  for (int off = 1; off <= 8; off <<= 1)
#pragma unroll
    for (int r = 0; r < 4; ++r) lsum[r] += __shfl_xor(lsum[r], off);
#pragma unroll
  for (int r = 0; r < 4; ++r) lsum[r] = 1.f / lsum[r];
#pragma unroll
  for (int dt = 0; dt < 4; ++dt)
#pragma unroll
    for (int r = 0; r < 4; ++r) {
      size_t row = (size_t)b * 2048 + q0 + quad * 4 + r;
      attnO[row * 512 + h * 64 + dt * 16 + l15] = f2bf(O[dt][r] * lsum[r]);
    }
#undef ATTN_STAGE
#undef ATTN_LOADB
#undef ATTN_BODY
}

// ---------------- K3: output projection (fp32 out) ----------------

__global__ __launch_bounds__(256) void gemm_out(const short* __restrict__ A,
                                                const short* __restrict__ BT,
                                                float* __restrict__ out) {
  __shared__ short As[2][128][32];
  __shared__ short Bs[2][128][32];
  const int t = threadIdx.x;
  const int w = t >> 6, lane = t & 63, l15 = lane & 15, quad = lane >> 4;
  const int wm = (w & 1) * 64, wn = (w >> 1) * 64;
  const int m0 = blockIdx.y * 128, n0 = blockIdx.x * 128;
  f32x4 acc[4][4];
#pragma unroll
  for (int i = 0; i < 4; ++i)
#pragma unroll
    for (int j = 0; j < 4; ++j) acc[i][j] = (f32x4){0.f, 0.f, 0.f, 0.f};

  gemm128_async(A, BT, m0, n0, (char*)&As[0][0][0], (char*)&Bs[0][0][0], acc);

#pragma unroll
  for (int i = 0; i < 4; ++i)
#pragma unroll
    for (int j = 0; j < 4; ++j)
#pragma unroll
      for (int r = 0; r < 4; ++r)
        out[(size_t)(m0 + wm + i * 16 + quad * 4 + r) * 512 + n0 + wn + j * 16 + l15] =
            acc[i][j][r];
}

// ---------------- launch ----------------

extern "C" void kernel_launch(void* const* d_in, const int* in_sizes, int n_in,
                              void* d_out, int out_size, void* d_ws, size_t ws_size,
                              hipStream_t stream) {
  (void)in_sizes; (void)n_in; (void)out_size; (void)ws_size;
  const float* x        = (const float*)d_in[0];
  const float* pos_bias = (const float*)d_in[1];
  const float* w_qkv    = (const float*)d_in[2];
  const float* w_out    = (const float*)d_in[3];
  float* out = (float*)d_out;

  short* ws = (short*)d_ws;
  const size_t SEG = (size_t)32 * 2048 * 64;   // 4.19M elems
  short* q_ws  = ws;
  short* k_ws  = q_ws + SEG;
  short* v_t   = k_ws + SEG;
  short* attnO = v_t + SEG;
  short* xbf   = attnO + SEG;                  // [8192][512]
  short* wqkvT = xbf + SEG;                    // [1536][512]
  short* woutT = wqkvT + (size_t)1536 * 512;   // [512][512]

  cvt_bf16<<<2048, 256, 0, stream>>>(x, xbf);
  transpose_cvt<<<dim3(24, 8), 256, 0, stream>>>(w_qkv, wqkvT, 512, 1536);
  transpose_cvt<<<dim3(8, 8), 256, 0, stream>>>(w_out, woutT, 512, 512);
  gemm_qkv<<<dim3(12, 64), 256, 0, stream>>>(xbf, wqkvT, q_ws, k_ws, v_t);
  attn_kernel<<<1024, 256, 0, stream>>>(q_ws, k_ws, v_t, pos_bias, attnO);
  gemm_out<<<dim3(4, 64), 256, 0, stream>>>(attnO, woutT, out);
}

// Round 8
// 360.212 us; speedup vs baseline: 1.2842x; 1.0241x over previous
//
#include <hip/hip_runtime.h>

typedef short bf16x8 __attribute__((ext_vector_type(8)));
typedef float f32x4 __attribute__((ext_vector_type(4)));

#define MFMA16(a, b, c) __builtin_amdgcn_mfma_f32_16x16x32_bf16(a, b, c, 0, 0, 0)

__device__ __forceinline__ short f2bf(float f) {
  unsigned u = __builtin_bit_cast(unsigned, f);
  u += 0x7fffu + ((u >> 16) & 1u);   // round-to-nearest-even
  return (short)(u >> 16);
}

// async global->LDS, 16B per lane; LDS dest is wave-uniform base (+ lane*16 by HW)
__device__ __forceinline__ void gload16(const void* g, void* l) {
  __builtin_amdgcn_global_load_lds(
      (const __attribute__((address_space(1))) void*)g,
      (__attribute__((address_space(3))) void*)l, 16, 0, 0);
}

// Problem sizes (fixed)
// B=4, N=2048, D=512, H=8, DH=64, M = B*N = 8192, 3*H*DH = 1536
#define L2E 1.44269504088896f

// ---------------- prep kernels (verified R4 versions) ----------------

__global__ __launch_bounds__(256) void cvt_bf16(const float* __restrict__ in,
                                                short* __restrict__ out) {
  size_t i = ((size_t)blockIdx.x * 256 + threadIdx.x) * 8;
  const float4* p = (const float4*)(in + i);
  float4 a = p[0], b = p[1];
  bf16x8 v;
  v[0] = f2bf(a.x); v[1] = f2bf(a.y); v[2] = f2bf(a.z); v[3] = f2bf(a.w);
  v[4] = f2bf(b.x); v[5] = f2bf(b.y); v[6] = f2bf(b.z); v[7] = f2bf(b.w);
  *(bf16x8*)(out + i) = v;
}

// in: fp32 [K][N] -> out: bf16 [N][K]
__global__ __launch_bounds__(256) void transpose_cvt(const float* __restrict__ in,
                                                     short* __restrict__ out,
                                                     int K, int N) {
  __shared__ short Ts[64][72];
  const int t = threadIdx.x;
  const int k0 = blockIdx.y * 64, n1 = blockIdx.x * 64;
  const int kk = t >> 2, nq = (t & 3) * 16;
  const float* src = in + (size_t)(k0 + kk) * N + n1 + nq;
#pragma unroll
  for (int i = 0; i < 16; ++i) Ts[nq + i][kk] = f2bf(src[i]);
  __syncthreads();
  const int n = t >> 2, kq = (t & 3) * 16;
  short* dst = out + (size_t)(n1 + n) * K + k0 + kq;
  *(bf16x8*)dst = *(const bf16x8*)&Ts[n][kq];
  *(bf16x8*)(dst + 8) = *(const bf16x8*)&Ts[n][kq + 8];
}

// ---------------- shared async GEMM mainloop: C[128x128] tile, K=512 ----------------
// (verified R7 version)

__device__ __forceinline__ void gemm128_async(const short* __restrict__ A,
                                              const short* __restrict__ BT,
                                              int m0, int n0,
                                              char* As, char* Bs,
                                              f32x4 acc[4][4]) {
  const int t = threadIdx.x;
  const int w = t >> 6, lane = t & 63, l15 = lane & 15, quad = lane >> 4;
  const int wm = (w & 1) * 64, wn = (w >> 1) * 64;
  const int scol = ((lane & 3) ^ ((lane >> 3) & 3)) << 4;
  const char* ag = (const char*)A + (size_t)(m0 + w * 32 + (lane >> 2)) * 1024 + scol;
  const char* bg = (const char*)BT + (size_t)(n0 + w * 32 + (lane >> 2)) * 1024 + scol;
  char* al = As + w * 2048;
  char* bl = Bs + w * 2048;
  const int rsw = (quad ^ ((l15 >> 1) & 3)) << 4;
  const int ra = (wm + l15) * 64 + rsw;
  const int rb = (wn + l15) * 64 + rsw;

#define GQ_STAGE(BUF, KB)                                                      \
  do {                                                                         \
    gload16(ag + (KB), al + (BUF) * 8192);                                     \
    gload16(ag + 16384 + (KB), al + (BUF) * 8192 + 1024);                      \
    gload16(bg + (KB), bl + (BUF) * 8192);                                     \
    gload16(bg + 16384 + (KB), bl + (BUF) * 8192 + 1024);                      \
  } while (0)

  GQ_STAGE(0, 0);
  __syncthreads();
#pragma unroll 2
  for (int s = 0; s < 16; ++s) {
    const int buf = s & 1;
    if (s < 15) GQ_STAGE(buf ^ 1, (s + 1) * 64);
    bf16x8 af[4], bfr[4];
#pragma unroll
    for (int i = 0; i < 4; ++i)
      af[i] = *(const bf16x8*)(As + buf * 8192 + ra + i * 1024);
#pragma unroll
    for (int j = 0; j < 4; ++j)
      bfr[j] = *(const bf16x8*)(Bs + buf * 8192 + rb + j * 1024);
#pragma unroll
    for (int i = 0; i < 4; ++i)
#pragma unroll
      for (int j = 0; j < 4; ++j)
        acc[i][j] = MFMA16(af[i], bfr[j], acc[i][j]);
    __syncthreads();
  }
#undef GQ_STAGE
}

// ---------------- K1: QKV projection ----------------

__global__ __launch_bounds__(256) void gemm_qkv(const short* __restrict__ A,
                                                const short* __restrict__ BT,
                                                short* __restrict__ q_ws,
                                                short* __restrict__ k_ws,
                                                short* __restrict__ v_t) {
  __shared__ short As[2][128][32];
  __shared__ short Bs[2][128][32];
  __shared__ short Ts[64][136];
  const int t = threadIdx.x;
  const int w = t >> 6, lane = t & 63, l15 = lane & 15, quad = lane >> 4;
  const int wm = (w & 1) * 64, wn = (w >> 1) * 64;
  const int m0 = blockIdx.y * 128, n0 = blockIdx.x * 128;
  f32x4 acc[4][4];
#pragma unroll
  for (int i = 0; i < 4; ++i)
#pragma unroll
    for (int j = 0; j < 4; ++j) acc[i][j] = (f32x4){0.f, 0.f, 0.f, 0.f};

  gemm128_async(A, BT, m0, n0, (char*)&As[0][0][0], (char*)&Bs[0][0][0], acc);

  const int which = n0 >> 9;            // 0=q 1=k 2=v
  const int b = m0 >> 11, seq0 = m0 & 2047;
  if (which < 2) {
    short* dst = (which == 0) ? q_ws : k_ws;
    const float scale = (which == 0) ? (0.125f * L2E) : 1.0f;
#pragma unroll
    for (int i = 0; i < 4; ++i)
#pragma unroll
      for (int j = 0; j < 4; ++j)
#pragma unroll
        for (int r = 0; r < 4; ++r) {
          int m_loc = wm + i * 16 + quad * 4 + r;
          int col = n0 + wn + j * 16 + l15;
          int h = (col >> 6) & 7, d = col & 63;
          dst[((size_t)(b * 8 + h) * 2048 + seq0 + m_loc) * 64 + d] =
              f2bf(acc[i][j][r] * scale);
        }
  } else {
    for (int half = 0; half < 2; ++half) {
      __syncthreads();
      if ((w >> 1) == half) {
#pragma unroll
        for (int i = 0; i < 4; ++i)
#pragma unroll
          for (int j = 0; j < 4; ++j)
#pragma unroll
            for (int r = 0; r < 4; ++r)
              Ts[j * 16 + l15][wm + i * 16 + quad * 4 + r] = f2bf(acc[i][j][r]);
      }
      __syncthreads();
      const int hd = ((n0 + half * 64) >> 6) & 7;
      const int dp = t >> 2, sq = (t & 3) * 32;
      short* dstp = v_t + ((size_t)(b * 8 + hd) * 64 + dp) * 2048 + seq0 + sq;
#pragma unroll
      for (int u = 0; u < 4; ++u)
        *(bf16x8*)(dstp + u * 8) = *(const bf16x8*)&Ts[dp][sq + u * 8];
    }
  }
}

// ---------------- K2: fused flash attention (no-max softmax) ----------------
// v5 = R4/R7 structure with two attn-only changes:
//  (a) counted-vmcnt barrier (T4): body-end __syncthreads() (vmcnt(0) drain)
//      -> sched_barrier(0); s_waitcnt vmcnt(16); s_barrier; sched_barrier(0).
//      In-order vmcnt retirement: the 4 K/V global_load_lds issued at body
//      top (oldest) must retire; the 16 bias dwords (newest) ride across the
//      barrier until their registers are consumed mid-next-body.  Cross-wave
//      LDS deps are only Ks/Vs (vmcnt-tracked); Pw is per-wave (in-order).
//      Extra unexpected vmem ops can only over-wait (safe).
//  (b) amdgpu_waves_per_eu(4,4): LDS caps occupancy at 4 blocks/CU (16
//      waves/CU) which is compatible with 128 VGPRs; stops the compiler's
//      64-VGPR squeeze that produced ~43 MB of scratch spills (WRITE_SIZE
//      52 MB vs 8.4 MB of actual output in R7).

#define ATTN_STAGE(BUFD, J0N)                                                  \
  do {                                                                         \
    _Pragma("unroll") for (int i_ = 0; i_ < 2; ++i_) {                         \
      const int ch_ = w * 2 + i_;                                              \
      const int off_ = ch_ * 1024 + lane * 16;                                 \
      const int row_ = off_ >> 7;                                              \
      const int col_ = (off_ & 127) ^ ((row_ & 7) << 4);                       \
      const char* gk_ = (const char*)k_ws +                                    \
          ((size_t)bh * 2048 + (size_t)(J0N) + row_) * 128 + col_;             \
      const char* gv_ = (const char*)v_t +                                     \
          ((size_t)bh * 64 + row_) * 4096 + (size_t)(J0N) * 2 + col_;          \
      gload16(gk_, (char*)&Ks[BUFD][0][0] + ch_ * 1024);                       \
      gload16(gv_, (char*)&Vs[BUFD][0][0] + ch_ * 1024);                       \
    }                                                                          \
  } while (0)

#define ATTN_LOADB(BV, J0N)                                                    \
  do {                                                                         \
    _Pragma("unroll") for (int nt_ = 0; nt_ < 4; ++nt_)                        \
        _Pragma("unroll") for (int r_ = 0; r_ < 4; ++r_)                       \
            BV[nt_][r_] = brow[r_][(J0N) + nt_ * 16];                          \
  } while (0)

#define ATTN_BODY(BUFC, BVC, BVN, J0N, DONEXT)                                 \
  do {                                                                         \
    if (DONEXT) {                                                              \
      ATTN_STAGE((BUFC) ^ 1, (J0N));                                           \
      ATTN_LOADB(BVN, (J0N));                                                  \
    }                                                                          \
    f32x4 S_[4];                                                               \
    _Pragma("unroll") for (int nt_ = 0; nt_ < 4; ++nt_) {                      \
      const char* kb_ = (const char*)&Ks[BUFC][0][0] + (nt_ * 16 + l15) * 128; \
      bf16x8 k0_ = *(const bf16x8*)(kb_ + cs);                                 \
      bf16x8 k1_ = *(const bf16x8*)(kb_ + (cs ^ 64));                          \
      f32x4 s_ = (f32x4){0.f, 0.f, 0.f, 0.f};                                  \
      s_ = MFMA16(aQ0, k0_, s_);                                               \
      s_ = MFMA16(aQ1, k1_, s_);                                               \
      S_[nt_] = s_;                                                            \
    }                                                                          \
    _Pragma("unroll") for (int nt_ = 0; nt_ < 4; ++nt_) {                      \
      float p0_ = exp2f(fmaf(BVC[nt_][0], L2E, S_[nt_][0]));                   \
      float p1_ = exp2f(fmaf(BVC[nt_][1], L2E, S_[nt_][1]));                   \
      float p2_ = exp2f(fmaf(BVC[nt_][2], L2E, S_[nt_][2]));                   \
      float p3_ = exp2f(fmaf(BVC[nt_][3], L2E, S_[nt_][3]));                   \
      lsum[0] += p0_; lsum[1] += p1_; lsum[2] += p2_; lsum[3] += p3_;          \
      unsigned pk01_, pk23_;                                                   \
      asm("v_cvt_pk_bf16_f32 %0, %1, %2" : "=v"(pk01_) : "v"(p0_), "v"(p1_)); \
      asm("v_cvt_pk_bf16_f32 %0, %1, %2" : "=v"(pk23_) : "v"(p2_), "v"(p3_)); \
      char* pb_ = (char*)&Pw[w][0][0];                                         \
      const int c0_ = 2 * (nt_ * 16 + l15);                                    \
      const int q4_ = quad * 4;                                                \
      *(short*)(pb_ + (q4_ + 0) * 128 + (c0_ ^ (((q4_ + 0) & 7) << 4))) =      \
          (short)pk01_;                                                        \
      *(short*)(pb_ + (q4_ + 1) * 128 + (c0_ ^ (((q4_ + 1) & 7) << 4))) =      \
          (short)(pk01_ >> 16);                                                \
      *(short*)(pb_ + (q4_ + 2) * 128 + (c0_ ^ (((q4_ + 2) & 7) << 4))) =      \
          (short)pk23_;                                                        \
      *(short*)(pb_ + (q4_ + 3) * 128 + (c0_ ^ (((q4_ + 3) & 7) << 4))) =      \
          (short)(pk23_ >> 16);                                                \
    }                                                                          \
    {                                                                          \
      const char* pr_ = (const char*)&Pw[w][0][0] + l15 * 128;                 \
      bf16x8 aP0 = *(const bf16x8*)(pr_ + cs);                                 \
      bf16x8 aP1 = *(const bf16x8*)(pr_ + (cs ^ 64));                          \
      _Pragma("unroll") for (int dt_ = 0; dt_ < 4; ++dt_) {                    \
        const char* vb_ =                                                      \
            (const char*)&Vs[BUFC][0][0] + (dt_ * 16 + l15) * 128;             \
        bf16x8 v0_ = *(const bf16x8*)(vb_ + cs);                               \
        bf16x8 v1_ = *(const bf16x8*)(vb_ + (cs ^ 64));                        \
        O[dt_] = MFMA16(aP0, v0_, O[dt_]);                                     \
        O[dt_] = MFMA16(aP1, v1_, O[dt_]);                                     \
      }                                                                        \
    }                                                                          \
    __builtin_amdgcn_sched_barrier(0);                                         \
    asm volatile("s_waitcnt vmcnt(16)" ::: "memory");                          \
    __builtin_amdgcn_s_barrier();                                              \
    __builtin_amdgcn_sched_barrier(0);                                         \
  } while (0)

__global__ __launch_bounds__(256)
__attribute__((amdgpu_waves_per_eu(4, 4)))
void attn_kernel(const short* __restrict__ q_ws,
                 const short* __restrict__ k_ws,
                 const short* __restrict__ v_t,
                 const float* __restrict__ bias,
                 short* __restrict__ attnO) {
  __shared__ short Ks[2][64][64];   // [buf][key][d]   8KB x2
  __shared__ short Vs[2][64][64];   // [buf][d][seq]   8KB x2
  __shared__ short Pw[4][16][64];   // [wave][qrow][key] 8KB
  const int t = threadIdx.x;
  const int w = t >> 6, lane = t & 63, l15 = lane & 15, quad = lane >> 4;
  const int bid = blockIdx.x;
  const int h = bid & 7;                 // XCD = h under round-robin dispatch
  const int b = (bid >> 3) & 3;          // siblings 8 apart -> same XCD
  const int qb = bid >> 5;               // 0..31 (64-row q tiles)
  const int bh = b * 8 + h;
  const int q0 = qb * 64 + w * 16;
  const int cs = (quad * 16) ^ ((l15 & 7) << 4);   // shared LDS read swizzle

  const size_t qbase = ((size_t)bh * 2048 + q0 + l15) * 64 + quad * 8;
  bf16x8 aQ0 = *(const bf16x8*)(q_ws + qbase);
  bf16x8 aQ1 = *(const bf16x8*)(q_ws + qbase + 32);

  f32x4 O[4];
#pragma unroll
  for (int i = 0; i < 4; ++i) O[i] = (f32x4){0.f, 0.f, 0.f, 0.f};
  float lsum[4] = {0.f, 0.f, 0.f, 0.f};

  const float* brow[4];
#pragma unroll
  for (int r = 0; r < 4; ++r)
    brow[r] = bias + ((size_t)h * 2048 + q0 + quad * 4 + r) * 2048 + l15;

  float bvA[4][4], bvB[4][4];
  ATTN_STAGE(0, 0);
  ATTN_LOADB(bvA, 0);
  __syncthreads();

  for (int it = 0; it < 16; ++it) {
    const int j0 = it * 128;
    ATTN_BODY(0, bvA, bvB, j0 + 64, 1);
    ATTN_BODY(1, bvB, bvA, j0 + 128, (it < 15));
  }

  // one 16-lane reduction of l at the very end
#pragma unroll
  for (int off = 1; off <= 8; off <<= 1)
#pragma unroll
    for (int r = 0; r < 4; ++r) lsum[r] += __shfl_xor(lsum[r], off);
#pragma unroll
  for (int r = 0; r < 4; ++r) lsum[r] = 1.f / lsum[r];
#pragma unroll
  for (int dt = 0; dt < 4; ++dt)
#pragma unroll
    for (int r = 0; r < 4; ++r) {
      size_t row = (size_t)b * 2048 + q0 + quad * 4 + r;
      attnO[row * 512 + h * 64 + dt * 16 + l15] = f2bf(O[dt][r] * lsum[r]);
    }
#undef ATTN_STAGE
#undef ATTN_LOADB
#undef ATTN_BODY
}

// ---------------- K3: output projection (fp32 out) ----------------

__global__ __launch_bounds__(256) void gemm_out(const short* __restrict__ A,
                                                const short* __restrict__ BT,
                                                float* __restrict__ out) {
  __shared__ short As[2][128][32];
  __shared__ short Bs[2][128][32];
  const int t = threadIdx.x;
  const int w = t >> 6, lane = t & 63, l15 = lane & 15, quad = lane >> 4;
  const int wm = (w & 1) * 64, wn = (w >> 1) * 64;
  const int m0 = blockIdx.y * 128, n0 = blockIdx.x * 128;
  f32x4 acc[4][4];
#pragma unroll
  for (int i = 0; i < 4; ++i)
#pragma unroll
    for (int j = 0; j < 4; ++j) acc[i][j] = (f32x4){0.f, 0.f, 0.f, 0.f};

  gemm128_async(A, BT, m0, n0, (char*)&As[0][0][0], (char*)&Bs[0][0][0], acc);

#pragma unroll
  for (int i = 0; i < 4; ++i)
#pragma unroll
    for (int j = 0; j < 4; ++j)
#pragma unroll
      for (int r = 0; r < 4; ++r)
        out[(size_t)(m0 + wm + i * 16 + quad * 4 + r) * 512 + n0 + wn + j * 16 + l15] =
            acc[i][j][r];
}

// ---------------- launch ----------------

extern "C" void kernel_launch(void* const* d_in, const int* in_sizes, int n_in,
                              void* d_out, int out_size, void* d_ws, size_t ws_size,
                              hipStream_t stream) {
  (void)in_sizes; (void)n_in; (void)out_size; (void)ws_size;
  const float* x        = (const float*)d_in[0];
  const float* pos_bias = (const float*)d_in[1];
  const float* w_qkv    = (const float*)d_in[2];
  const float* w_out    = (const float*)d_in[3];
  float* out = (float*)d_out;

  short* ws = (short*)d_ws;
  const size_t SEG = (size_t)32 * 2048 * 64;   // 4.19M elems
  short* q_ws  = ws;
  short* k_ws  = q_ws + SEG;
  short* v_t   = k_ws + SEG;
  short* attnO = v_t + SEG;
  short* xbf   = attnO + SEG;                  // [8192][512]
  short* wqkvT = xbf + SEG;                    // [1536][512]
  short* woutT = wqkvT + (size_t)1536 * 512;   // [512][512]

  cvt_bf16<<<2048, 256, 0, stream>>>(x, xbf);
  transpose_cvt<<<dim3(24, 8), 256, 0, stream>>>(w_qkv, wqkvT, 512, 1536);
  transpose_cvt<<<dim3(8, 8), 256, 0, stream>>>(w_out, woutT, 512, 512);
  gemm_qkv<<<dim3(12, 64), 256, 0, stream>>>(xbf, wqkvT, q_ws, k_ws, v_t);
  attn_kernel<<<1024, 256, 0, stream>>>(q_ws, k_ws, v_t, pos_bias, attnO);
  gemm_out<<<dim3(4, 64), 256, 0, stream>>>(attnO, woutT, out);
}